// Round 9
// baseline (23635.934 us; speedup 1.0000x reference)
//
#include <hip/hip_runtime.h>
#include <cstdint>
#include <cstddef>

// RecurrentDecoder: 128 sequential GRU steps fused via x_t = h_t @ W_dec^T
// => gates = h @ W_eff^T (4096 gate cols + 256 decode cols), one GEMM/step.
// Round 15 == Round 12 resubmit (R12/R13/R14 never executed - GPU capacity).
// R5 post-mortem: 2 blocks/CU regressed (LDS port is the binding resource:
// ~11.4us LDS vs 4.65us MFMA per step; TLP doubled B-staging traffic).
// Changes vs R9 (2537us, 19.8us/step):
//  1. decode A-frags aliased: ad2[d] == af[2*wc+d]  (-18% LDS reads)
//  2. ONE barrier per K-iter (NBUF>=3 makes the post-MFMA barrier redundant)
//  3. NBUF=4 (16%4==0 -> step-invariant buffer<->set alignment), 3 sets in flight
//  4. cross-step B prestage: B sets 0-2 issued before the inter-block spin;
//     A sets 0-2 at top of each t-iter; raw post-spin s_barrier (no drain).
//     vmcnt ladder: ki=0->8; 1->13/12; 2..13->18/16; 14->9/8; 15->0.
// Geometry: 256 blocks = 8 mt x 32 cb; block tile [128 x 144], 4 waves (2x2),
// 1 block/CU. Fenceless coherence (R9-proven): h16 stores sc0|sc1, A-loads
// aux=17 (LLC), B cached in XCD L2, relaxed-atomic mt-group barrier.

#define HD 1024
#define OD 256
#define TS 128
#define NBUF 4
#define ABUF 16384
#define BBUF 18432

typedef _Float16 f16x8 __attribute__((ext_vector_type(8)));
typedef float f32x4 __attribute__((ext_vector_type(4)));

// aux: 0 = normal caching (L1+L2). 17 = sc0|sc1 = device-coherent: bypass
// stale L1/L2, serve from LLC (memory-side cache = coherence point).
template <int AUX>
__device__ __forceinline__ void gl_lds16(const void* g, void* l) {
  auto gp = reinterpret_cast<const __attribute__((address_space(1))) unsigned int*>(
      reinterpret_cast<uintptr_t>(g));
  auto lp = reinterpret_cast<__attribute__((address_space(3))) unsigned int*>(
      reinterpret_cast<uintptr_t>(l));
  __builtin_amdgcn_global_load_lds(gp, lp, 16, 0, AUX);
}

// device-scope write-through 2B store (reaches LLC before vmcnt retires)
__device__ __forceinline__ void st_h16_dev(_Float16* p, _Float16 v) {
  asm volatile("global_store_short %0, %1, off sc0 sc1"
               :: "v"(p), "v"(v) : "memory");
}

// ---------------- prep: build W_ws [32 cb][144 rows][1024 k] fp16 ----------------
__global__ __launch_bounds__(256) void prep_w(
    const float* __restrict__ Wih,   // [3072][256]
    const float* __restrict__ Whh,   // [3072][1024]
    const float* __restrict__ Wdec,  // [256][1024]
    _Float16* __restrict__ Wws)      // [32][144][1024]
{
  int blk = blockIdx.x, tid = threadIdx.x;
  int k0 = tid * 4;
  if (blk < 768) {                      // dot blocks: rows rr<96 (s in 0..2), 4 rows each
    int cbv[4], rrv[4], jg[4], jh[4];
    #pragma unroll
    for (int rsel = 0; rsel < 4; ++rsel) {
      int dj = blk * 4 + rsel;
      int cb = dj / 96, rr = dj % 96;
      int s = rr >> 5, wcol = (rr >> 4) & 1, p = rr & 15;
      int j = cb * 32 + wcol * 16 + p;
      cbv[rsel] = cb; rrv[rsel] = rr;
      jg[rsel] = s * 1024 + j;
      jh[rsel] = (s == 0) ? j : (s == 1 ? 1024 + j : -1);
    }
    float acc[4][4];
    #pragma unroll
    for (int a = 0; a < 4; ++a) { acc[a][0]=0.f; acc[a][1]=0.f; acc[a][2]=0.f; acc[a][3]=0.f; }
    for (int q = 0; q < 256; ++q) {
      float4 wd = *(const float4*)(Wdec + (size_t)q * 1024 + k0);
      #pragma unroll
      for (int a = 0; a < 4; ++a) {
        float w = Wih[(size_t)jg[a] * 256 + q];
        acc[a][0] += w * wd.x; acc[a][1] += w * wd.y;
        acc[a][2] += w * wd.z; acc[a][3] += w * wd.w;
      }
    }
    #pragma unroll
    for (int a = 0; a < 4; ++a) {
      if (jh[a] >= 0) {
        const float* wh = Whh + (size_t)jh[a] * 1024 + k0;
        acc[a][0] += wh[0]; acc[a][1] += wh[1];
        acc[a][2] += wh[2]; acc[a][3] += wh[3];
      }
      _Float16* dst = Wws + ((size_t)cbv[a] * 144 + rrv[a]) * 1024 + k0;
      dst[0] = (_Float16)acc[a][0]; dst[1] = (_Float16)acc[a][1];
      dst[2] = (_Float16)acc[a][2]; dst[3] = (_Float16)acc[a][3];
    }
  } else {                              // copy blocks: rows rr in 96..143
    #pragma unroll
    for (int rsel = 0; rsel < 4; ++rsel) {
      int cr = (blk - 768) * 4 + rsel;
      int cb = cr / 48, rr = 96 + cr % 48;
      _Float16* dst = Wws + ((size_t)cb * 144 + rr) * 1024 + k0;
      if (rr < 128) {                   // s=3: Whh[2048+j]
        int j = cb * 32 + ((rr >> 4) & 1) * 16 + (rr & 15);
        const float* src = Whh + (size_t)(2048 + j) * 1024 + k0;
        dst[0] = (_Float16)src[0]; dst[1] = (_Float16)src[1];
        dst[2] = (_Float16)src[2]; dst[3] = (_Float16)src[3];
      } else if (rr < 136) {
        const float* src = Wdec + (size_t)(cb * 8 + rr - 128) * 1024 + k0;
        dst[0] = (_Float16)src[0]; dst[1] = (_Float16)src[1];
        dst[2] = (_Float16)src[2]; dst[3] = (_Float16)src[3];
      } else {
        dst[0] = (_Float16)0.f; dst[1] = (_Float16)0.f;
        dst[2] = (_Float16)0.f; dst[3] = (_Float16)0.f;
      }
    }
  }
}

__global__ __launch_bounds__(256) void prep_bias(
    const float* __restrict__ Wih,
    const float* __restrict__ bih, const float* __restrict__ bhh,
    const float* __restrict__ bdec_in,
    float* __restrict__ br, float* __restrict__ bz, float* __restrict__ bin_,
    float* __restrict__ bhn, float* __restrict__ bdec,
    unsigned int* __restrict__ ctr)
{
  int j = blockIdx.x * 256 + threadIdx.x;   // grid 4 -> j < 1024
  if (blockIdx.x == 0) ctr[threadIdx.x] = 0u;   // reset per-mt barrier counters
  float bc0 = 0.f, bc1 = 0.f, bc2 = 0.f;
  for (int q = 0; q < 256; ++q) {
    float bd = bdec_in[q];
    bc0 += Wih[(size_t)j * 256 + q] * bd;
    bc1 += Wih[(size_t)(1024 + j) * 256 + q] * bd;
    bc2 += Wih[(size_t)(2048 + j) * 256 + q] * bd;
  }
  br[j]  = bih[j]        + bhh[j]        + bc0;
  bz[j]  = bih[1024 + j] + bhh[1024 + j] + bc1;
  bin_[j]= bih[2048 + j] + bc2;
  bhn[j] = bhh[2048 + j];
  if (j < 256) bdec[j] = bdec_in[j];
}

__global__ __launch_bounds__(256) void prep_h(
    const float* __restrict__ h0, _Float16* __restrict__ h16)
{
  int i = blockIdx.x * 256 + threadIdx.x;
  h16[i] = (_Float16)h0[i];
}

// ---------------- persistent fused kernel (cooperative, 1 block/CU) ----------------
// grid 256 = mt(8)*32 + cb(32); 256 thr = 4 waves (2x2 over [128x128] gates).
// LDS: 4 A bufs (16384 B) then 4 B bufs (18432 B). Per buffer: [row][8 kgroups
// of 16B], row stride 128 B; kgroup XOR-swizzled by (row&7), folded into the
// DMA's per-lane GLOBAL address so LDS destinations stay lane-linear.
// K-loop: ONE raw s_barrier per iter; counted vmcnt ladder (L=9 waves 0,1 /
// 8 waves 2,3; B-only Lb=5/4): ki=0->8; 1->13/12; 2..13->18/16; 14->9/8; 15->0.
__global__ __launch_bounds__(256, 1) void fused_gru(
    const _Float16* __restrict__ Wws,
    const float* __restrict__ br, const float* __restrict__ bz,
    const float* __restrict__ bin_, const float* __restrict__ bhn,
    const float* __restrict__ bdec,
    const float* __restrict__ h0,
    _Float16* __restrict__ h16A, _Float16* __restrict__ h16B,
    float* __restrict__ out,
    unsigned int* __restrict__ ctr)
{
  __shared__ __align__(16) char lds[NBUF * (ABUF + BBUF)];   // 139264 B

  const int tid = threadIdx.x;
  const int wave = tid >> 6, lane = tid & 63;
  const int mt = blockIdx.x >> 5, cb = blockIdx.x & 31;
  const int wr = wave >> 1, wc = wave & 1;
  const int col16 = lane & 15, quad = lane >> 4;

  const _Float16* __restrict__ slab = Wws + (size_t)cb * (144 * 1024);

  // DMA chunk geometry: chunk m (16 B) covers row r=m>>3, lds-kgroup c=m&7;
  // global kgroup g = c ^ (r&7) (swizzle). Wave w, issue j covers chunks
  // (w*4+j)*64 + lane. Extra B chunks 1024+tid (tid<128) cover rows 128..143.
  int offs[4];
  #pragma unroll
  for (int jj = 0; jj < 4; ++jj) {
    int m = (wave * 4 + jj) * 64 + lane;
    int r = m >> 3, c = m & 7, g = c ^ (r & 7);
    offs[jj] = r * 1024 + g * 8;       // element (half) offset
  }
  int offE;
  { int m = 1024 + tid; int r = m >> 3, c = m & 7, g = c ^ (r & 7);
    offE = r * 1024 + g * 8; }         // valid when tid < 128 (waves 0,1)

  const int swz = (quad ^ (col16 & 7)) << 4;   // ds_read swizzled col base; K-hi = ^64 B

  // loop-invariant epilogue constants (loaded once)
  const int j = cb * 32 + wc * 16 + col16;     // gate col 0..1023
  const float vbr = br[j], vbz = bz[j], vbi = bin_[j], vbh = bhn[j];
  const float vb = bdec[cb * 8 + (col16 & 7)]; // used only when col16 < 8

  // fp32 hold carried in registers across all 128 steps (C/D layout:
  // n = lane&15, m = quad*4 + reg). Seeded from h0.
  float hold[4][4];
  #pragma unroll
  for (int fm = 0; fm < 4; ++fm) {
    const int mbase = mt * 128 + 64 * wr + 16 * fm + quad * 4;
    #pragma unroll
    for (int ri = 0; ri < 4; ++ri)
      hold[fm][ri] = h0[(size_t)(mbase + ri) * 1024 + j];
  }
  // drain preloads so the vmcnt ledger starts clean
  asm volatile("s_waitcnt vmcnt(0)" ::: "memory");

  // B-only staging (weights, L2-cached): Lb = 5 (waves 0,1) / 4 (waves 2,3)
  auto issue_B = [&](int bsel, int kc) {
    char* Bb = lds + NBUF * ABUF + bsel * BBUF;
    #pragma unroll
    for (int jj = 0; jj < 4; ++jj)
      gl_lds16<0>(slab + offs[jj] + kc, Bb + (wave * 4 + jj) * 1024);
    if (wave < 2)
      gl_lds16<0>(slab + offE + kc, Bb + 16384 + wave * 1024);
  };

  const f32x4 fzero = {0.f, 0.f, 0.f, 0.f};

  // pre-loop: B sets 0..2 in flight (same every step)
  issue_B(0, 0);
  issue_B(1, 64);
  issue_B(2, 128);

  #pragma unroll 1
  for (int t = 0; t <= TS; ++t) {      // t=TS: decode-only pass for out[:,127,:]
    const _Float16* __restrict__ Abase =
        ((t & 1) ? h16B : h16A) + (size_t)mt * (128 * 1024);
    _Float16* __restrict__ o16 = (t & 1) ? h16A : h16B;

    // A-only staging (h16, device-coherent from LLC): 4 loads/set/wave
    auto issue_A = [&](int bsel, int kc) {
      char* Ab = lds + bsel * ABUF;
      #pragma unroll
      for (int jj = 0; jj < 4; ++jj)
        gl_lds16<17>(Abase + offs[jj] + kc, Ab + (wave * 4 + jj) * 1024);
    };
    auto issue_set = [&](int bsel, int kc) {
      char* Ab = lds + bsel * ABUF;
      char* Bb = lds + NBUF * ABUF + bsel * BBUF;
      #pragma unroll
      for (int jj = 0; jj < 4; ++jj) {
        gl_lds16<17>(Abase + offs[jj] + kc, Ab + (wave * 4 + jj) * 1024);
        gl_lds16<0>(slab  + offs[jj] + kc, Bb + (wave * 4 + jj) * 1024);
      }
      if (wave < 2)
        gl_lds16<0>(slab + offE + kc, Bb + 16384 + wave * 1024);
    };

    f32x4 accG[4][4]; f32x4 accD[2];
    #pragma unroll
    for (int i = 0; i < 4; ++i)
      #pragma unroll
      for (int jj = 0; jj < 4; ++jj) accG[i][jj] = fzero;
    accD[0] = fzero; accD[1] = fzero;

    // prologue: A for the 3 prestaged-B sets
    issue_A(0, 0);
    issue_A(1, 64);
    issue_A(2, 128);

    #pragma unroll 1
    for (int ki = 0; ki < 16; ++ki) {
      const int cur = ki & 3;
      // counted-vmcnt ladder (derivation in header comment):
      __builtin_amdgcn_sched_barrier(0);
      if (ki == 0) {
        asm volatile("s_waitcnt vmcnt(8)" ::: "memory");
      } else if (ki == 1) {
        if (wave < 2) asm volatile("s_waitcnt vmcnt(13)" ::: "memory");
        else          asm volatile("s_waitcnt vmcnt(12)" ::: "memory");
      } else if (ki <= 13) {
        if (wave < 2) asm volatile("s_waitcnt vmcnt(18)" ::: "memory");
        else          asm volatile("s_waitcnt vmcnt(16)" ::: "memory");
      } else if (ki == 14) {
        if (wave < 2) asm volatile("s_waitcnt vmcnt(9)" ::: "memory");
        else          asm volatile("s_waitcnt vmcnt(8)" ::: "memory");
      } else {
        asm volatile("s_waitcnt vmcnt(0)" ::: "memory");
      }
      __builtin_amdgcn_s_barrier();    // set-ki DMAs complete in all waves; all
                                       // waves finished READING buf (ki-1)&3
      __builtin_amdgcn_sched_barrier(0);

      if (ki <= 12) issue_set((ki + 3) & 3, (ki + 3) * 64);  // into freed buf

      const char* As = lds + cur * ABUF;
      const char* Bs = lds + NBUF * ABUF + cur * BBUF;

      #pragma unroll
      for (int half = 0; half < 2; ++half) {
        const int sz = swz ^ (half << 6);             // column byte offset
        f16x8 af[4], bg[4], bdv;
        #pragma unroll
        for (int fm = 0; fm < 4; ++fm)
          af[fm] = *(const f16x8*)(As + (64 * wr + 16 * fm + col16) * 128 + sz);
        #pragma unroll
        for (int fn = 0; fn < 4; ++fn)
          bg[fn] = *(const f16x8*)(Bs + (32 * fn + wc * 16 + col16) * 128 + sz);
        bdv = *(const f16x8*)(Bs + (128 + col16) * 128 + sz);

        __builtin_amdgcn_s_setprio(1);               // T5: favor MFMA-entering wave
        #pragma unroll
        for (int fm = 0; fm < 4; ++fm)
          #pragma unroll
          for (int fn = 0; fn < 4; ++fn)
            accG[fm][fn] = __builtin_amdgcn_mfma_f32_16x16x32_f16(af[fm], bg[fn], accG[fm][fn], 0, 0, 0);
        // decode A-frags alias gate A-frags: rows 32*wave+16*d == 64*wr+16*(2*wc+d)
        accD[0] = __builtin_amdgcn_mfma_f32_16x16x32_f16(af[2 * wc],     bdv, accD[0], 0, 0, 0);
        accD[1] = __builtin_amdgcn_mfma_f32_16x16x32_f16(af[2 * wc + 1], bdv, accD[1], 0, 0, 0);
        __builtin_amdgcn_s_setprio(0);
      }
      // no trailing barrier: next iter's top barrier provides read-protection
    }

    // epilogue: gate math in registers; hold stays in VGPRs; h16 stores are
    // device write-through (sc0 sc1) so no cache flush is ever needed.
    if (t < TS) {
      #pragma unroll
      for (int fm = 0; fm < 4; ++fm) {
        const int mbase = mt * 128 + 64 * wr + 16 * fm + quad * 4;
        #pragma unroll
        for (int ri = 0; ri < 4; ++ri) {
          const int m = mbase + ri;
          float rg = 1.f / (1.f + __expf(-(accG[fm][0][ri] + vbr)));
          float zg = 1.f / (1.f + __expf(-(accG[fm][1][ri] + vbz)));
          float nn = tanhf(accG[fm][2][ri] + vbi + rg * (accG[fm][3][ri] + vbh));
          float hnew = (1.f - zg) * nn + zg * hold[fm][ri];
          hold[fm][ri] = hnew;
          st_h16_dev(o16 + (size_t)m * 1024 + j, (_Float16)hnew);
        }
      }
    }
    if (t > 0 && col16 < 8) {          // decode of h_{t-1} -> out[:, t-1, :]
      const int oc = cb * 8 + col16;
      #pragma unroll
      for (int d = 0; d < 2; ++d) {
        const int mbase = mt * 128 + 32 * wave + 16 * d + quad * 4;
        #pragma unroll
        for (int ri = 0; ri < 4; ++ri) {
          const int m = mbase + ri;
          out[(size_t)m * (TS * OD) + (size_t)(t - 1) * OD + oc] = accD[d][ri] + vb;
        }
      }
    }

    // per-mt inter-block barrier (32 blocks share an mt group), FENCELESS.
    // Release: __syncthreads' implicit vmcnt(0) drains sc1 stores to LLC, then
    // tid0's relaxed agent atomic. B for the NEXT step is prestaged between
    // the drain and the spin so it flies during the barrier wait. Acquire:
    // spin on relaxed agent load; post-spin sync is a RAW s_barrier (no
    // drain) so prestaged B stays in flight; A-loads are aux=17 (LLC-coherent).
    if (t < TS) {
      __syncthreads();
      issue_B(0, 0);
      issue_B(1, 64);
      issue_B(2, 128);
      if (tid == 0) {
        __hip_atomic_fetch_add(&ctr[mt * 32], 1u, __ATOMIC_RELAXED, __HIP_MEMORY_SCOPE_AGENT);
        while (__hip_atomic_load(&ctr[mt * 32], __ATOMIC_RELAXED, __HIP_MEMORY_SCOPE_AGENT)
               < 32u * (unsigned)(t + 1)) {
          __builtin_amdgcn_s_sleep(1);
        }
      }
      __builtin_amdgcn_s_barrier();
      __builtin_amdgcn_sched_barrier(0);
    }
  }
}

// ---------------- fallback step kernel (proven multi-launch path) ----------------
// Used only if the cooperative launch is rejected at enqueue time.
__global__ __launch_bounds__(256, 1) void step_kernel(
    const _Float16* __restrict__ Wws,
    const float* __restrict__ br, const float* __restrict__ bz,
    const float* __restrict__ bin_, const float* __restrict__ bhn,
    const float* __restrict__ bdec,
    const _Float16* __restrict__ h_in16, const float* __restrict__ h_in32,
    _Float16* __restrict__ h_out16, float* __restrict__ h_out32,
    float* __restrict__ out, int t)
{
  __shared__ __align__(16) char lds[2 * 16384 + 2 * 18432];

  const int tid = threadIdx.x;
  const int wave = tid >> 6, lane = tid & 63;
  const int mt = blockIdx.x >> 5, cb = blockIdx.x & 31;
  const int wr = wave >> 1, wc = wave & 1;
  const int col16 = lane & 15, quad = lane >> 4;

  const _Float16* __restrict__ slab  = Wws + (size_t)cb * (144 * 1024);
  const _Float16* __restrict__ Abase = h_in16 + (size_t)mt * (128 * 1024);

  int offs[4];
  #pragma unroll
  for (int jj = 0; jj < 4; ++jj) {
    int m = (wave * 4 + jj) * 64 + lane;
    int r = m >> 3, c = m & 7, g = c ^ (r & 7);
    offs[jj] = r * 1024 + g * 8;
  }
  int offE;
  { int m = 1024 + tid; int r = m >> 3, c = m & 7, g = c ^ (r & 7);
    offE = r * 1024 + g * 8; }

  const int swz = (quad ^ (col16 & 7)) << 4;

  f32x4 accG[4][4]; f32x4 accD[2];
  const f32x4 fzero = {0.f, 0.f, 0.f, 0.f};
  #pragma unroll
  for (int i = 0; i < 4; ++i)
    #pragma unroll
    for (int jj = 0; jj < 4; ++jj) accG[i][jj] = fzero;
  accD[0] = fzero; accD[1] = fzero;

  auto issue_dma = [&](int bsel, int kc) {
    char* Ab = lds + bsel * 16384;
    char* Bb = lds + 32768 + bsel * 18432;
    #pragma unroll
    for (int jj = 0; jj < 4; ++jj) {
      gl_lds16<0>(Abase + offs[jj] + kc, Ab + (wave * 4 + jj) * 1024);
      gl_lds16<0>(slab  + offs[jj] + kc, Bb + (wave * 4 + jj) * 1024);
    }
    if (wave < 2)
      gl_lds16<0>(slab + offE + kc, Bb + 16384 + wave * 1024);
  };

  issue_dma(0, 0);
  __syncthreads();

  #pragma unroll 1
  for (int ki = 0; ki < 16; ++ki) {
    const int cur = ki & 1;
    if (ki < 15) issue_dma(cur ^ 1, (ki + 1) * 64);
    const char* As = lds + cur * 16384;
    const char* Bs = lds + 32768 + cur * 18432;

    #pragma unroll
    for (int half = 0; half < 2; ++half) {
      const int sz = swz ^ (half << 6);
      f16x8 af[4], bg[4], bdv;
      #pragma unroll
      for (int fm = 0; fm < 4; ++fm)
        af[fm] = *(const f16x8*)(As + (64 * wr + 16 * fm + col16) * 128 + sz);
      #pragma unroll
      for (int fn = 0; fn < 4; ++fn)
        bg[fn] = *(const f16x8*)(Bs + (32 * fn + wc * 16 + col16) * 128 + sz);
      bdv = *(const f16x8*)(Bs + (128 + col16) * 128 + sz);

      #pragma unroll
      for (int fm = 0; fm < 4; ++fm)
        #pragma unroll
        for (int fn = 0; fn < 4; ++fn)
          accG[fm][fn] = __builtin_amdgcn_mfma_f32_16x16x32_f16(af[fm], bg[fn], accG[fm][fn], 0, 0, 0);
      accD[0] = __builtin_amdgcn_mfma_f32_16x16x32_f16(af[2 * wc],     bdv, accD[0], 0, 0, 0);
      accD[1] = __builtin_amdgcn_mfma_f32_16x16x32_f16(af[2 * wc + 1], bdv, accD[1], 0, 0, 0);
    }
    __syncthreads();
  }

  if (t < TS) {
    const int jj2 = cb * 32 + wc * 16 + col16;
    const float vbr = br[jj2], vbz = bz[jj2], vbi = bin_[jj2], vbh = bhn[jj2];
    #pragma unroll
    for (int fm = 0; fm < 4; ++fm) {
      const int mbase = mt * 128 + 64 * wr + 16 * fm + quad * 4;
      #pragma unroll
      for (int ri = 0; ri < 4; ++ri) {
        const int m = mbase + ri;
        float rg = 1.f / (1.f + __expf(-(accG[fm][0][ri] + vbr)));
        float zg = 1.f / (1.f + __expf(-(accG[fm][1][ri] + vbz)));
        float nn = tanhf(accG[fm][2][ri] + vbi + rg * (accG[fm][3][ri] + vbh));
        float hold = h_in32[(size_t)m * 1024 + jj2];
        float hnew = (1.f - zg) * nn + zg * hold;
        h_out32[(size_t)m * 1024 + jj2] = hnew;
        h_out16[(size_t)m * 1024 + jj2] = (_Float16)hnew;
      }
    }
  }
  if (t > 0 && col16 < 8) {
    const int oc = cb * 8 + col16;
    const float vb = bdec[oc];
    #pragma unroll
    for (int d = 0; d < 2; ++d) {
      const int mbase = mt * 128 + 32 * wave + 16 * d + quad * 4;
      #pragma unroll
      for (int ri = 0; ri < 4; ++ri) {
        const int m = mbase + ri;
        out[(size_t)m * (TS * OD) + (size_t)(t - 1) * OD + oc] = accD[d][ri] + vb;
      }
    }
  }
}

extern "C" void kernel_launch(void* const* d_in, const int* in_sizes, int n_in,
                              void* d_out, int out_size, void* d_ws, size_t ws_size,
                              hipStream_t stream) {
  const float* h0      = (const float*)d_in[0];   // [1,1024,1024]
  const float* Wih     = (const float*)d_in[1];   // [3072,256]
  const float* Whh     = (const float*)d_in[2];   // [3072,1024]
  const float* bih     = (const float*)d_in[3];   // [3072]
  const float* bhh     = (const float*)d_in[4];   // [3072]
  const float* Wdec    = (const float*)d_in[5];   // [256,1024]
  const float* bdec_in = (const float*)d_in[6];   // [256]
  float* out = (float*)d_out;                     // [1024,128,256] fp32

  char* ws = (char*)d_ws;
  _Float16* Wws = (_Float16*)ws;                         // 9,437,184 B
  float* br   = (float*)(ws + 9437184);
  float* bz   = (float*)(ws + 9437184 + 4096);
  float* bin_ = (float*)(ws + 9437184 + 8192);
  float* bhn  = (float*)(ws + 9437184 + 12288);
  float* bdec = (float*)(ws + 9437184 + 16384);
  _Float16* h16A = (_Float16*)(ws + 9461760);            // 2 MB
  _Float16* h16B = h16A + 1024 * 1024;                   // 2 MB
  unsigned int* ctr = (unsigned int*)(ws + 9461760 + 4194304);  // 1 KB
  float* h32A = (float*)(ws + 9461760 + 4194304 + 4096); // 4 MB (fallback only)
  float* h32B = h32A + 1024 * 1024;                      // 4 MB (fallback only)
  // total ws use ~21.9 MB

  prep_w<<<1152, 256, 0, stream>>>(Wih, Whh, Wdec, Wws);
  prep_bias<<<4, 256, 0, stream>>>(Wih, bih, bhh, bdec_in, br, bz, bin_, bhn, bdec, ctr);
  prep_h<<<4096, 256, 0, stream>>>(h0, h16A);

  void* kargs[] = {
    (void*)&Wws, (void*)&br, (void*)&bz, (void*)&bin_, (void*)&bhn, (void*)&bdec,
    (void*)&h0, (void*)&h16A, (void*)&h16B, (void*)&out, (void*)&ctr
  };
  hipError_t cerr = hipLaunchCooperativeKernel((void*)fused_gru, dim3(256), dim3(256),
                                               kargs, 0, stream);
  if (cerr != hipSuccess) {
    // Fallback: proven multi-launch path (uses fp32 h carry in memory).
    for (int t = 0; t <= TS; ++t) {
      const _Float16* in16 = (t & 1) ? h16B : h16A;
      const float*    in32 = (t == 0) ? h0 : ((t & 1) ? h32B : h32A);
      _Float16*       o16  = (t & 1) ? h16A : h16B;
      float*          o32  = (t & 1) ? h32A : h32B;
      step_kernel<<<256, 256, 0, stream>>>(Wws, br, bz, bin_, bhn, bdec,
                                           in16, in32, o16, o32, out, t);
    }
  }
}

// Round 13
// 2582.422 us; speedup vs baseline: 9.1526x; 9.1526x over previous
//
#include <hip/hip_runtime.h>
#include <cstdint>
#include <cstddef>

// RecurrentDecoder: 128 sequential GRU steps fused via x_t = h_t @ W_dec^T
// => gates = h @ W_eff^T (4096 gate cols + 256 decode cols), one GEMM/step.
// Round 19 == Round 16 resubmit (R16-R18 never executed - infra failures).
// R9-run post-mortem: R12's af[2*wc] (RUNTIME index into ext_vector array)
// sent af[] to scratch -> 23636us, VALU 52%, VGPR 216. Fix (this rev): wave-
// uniform select over STATIC indices (R10's proven 88-VGPR idiom):
//   adv0 = wc ? af[2] : af[0];  adv1 = wc ? af[3] : af[1];
// Everything else identical to R12 (correctness HW-validated in R9 run):
//  1. decode A-frags aliased via select  (-18% LDS reads vs R9)
//  2. ONE barrier per K-iter (NBUF>=3 makes the post-MFMA barrier redundant)
//  3. NBUF=4 (16%4==0 -> step-invariant buffer<->set alignment), 3 sets in flight
//  4. cross-step B prestage: B sets 0-2 issued before the inter-block spin;
//     A sets 0-2 at top of each t-iter; raw post-spin s_barrier (no drain).
//     vmcnt ladder: ki=0->8; 1->13/12; 2..13->18/16; 14->9/8; 15->0.
// Geometry: 256 blocks = 8 mt x 32 cb; block tile [128 x 144], 4 waves (2x2),
// 1 block/CU. Fenceless coherence (R9-proven): h16 stores sc0|sc1, A-loads
// aux=17 (LLC), B cached in XCD L2, relaxed-atomic mt-group barrier.

#define HD 1024
#define OD 256
#define TS 128
#define NBUF 4
#define ABUF 16384
#define BBUF 18432

typedef _Float16 f16x8 __attribute__((ext_vector_type(8)));
typedef float f32x4 __attribute__((ext_vector_type(4)));

// aux: 0 = normal caching (L1+L2). 17 = sc0|sc1 = device-coherent: bypass
// stale L1/L2, serve from LLC (memory-side cache = coherence point).
template <int AUX>
__device__ __forceinline__ void gl_lds16(const void* g, void* l) {
  auto gp = reinterpret_cast<const __attribute__((address_space(1))) unsigned int*>(
      reinterpret_cast<uintptr_t>(g));
  auto lp = reinterpret_cast<__attribute__((address_space(3))) unsigned int*>(
      reinterpret_cast<uintptr_t>(l));
  __builtin_amdgcn_global_load_lds(gp, lp, 16, 0, AUX);
}

// device-scope write-through 2B store (reaches LLC before vmcnt retires)
__device__ __forceinline__ void st_h16_dev(_Float16* p, _Float16 v) {
  asm volatile("global_store_short %0, %1, off sc0 sc1"
               :: "v"(p), "v"(v) : "memory");
}

// ---------------- prep: build W_ws [32 cb][144 rows][1024 k] fp16 ----------------
__global__ __launch_bounds__(256) void prep_w(
    const float* __restrict__ Wih,   // [3072][256]
    const float* __restrict__ Whh,   // [3072][1024]
    const float* __restrict__ Wdec,  // [256][1024]
    _Float16* __restrict__ Wws)      // [32][144][1024]
{
  int blk = blockIdx.x, tid = threadIdx.x;
  int k0 = tid * 4;
  if (blk < 768) {                      // dot blocks: rows rr<96 (s in 0..2), 4 rows each
    int cbv[4], rrv[4], jg[4], jh[4];
    #pragma unroll
    for (int rsel = 0; rsel < 4; ++rsel) {
      int dj = blk * 4 + rsel;
      int cb = dj / 96, rr = dj % 96;
      int s = rr >> 5, wcol = (rr >> 4) & 1, p = rr & 15;
      int j = cb * 32 + wcol * 16 + p;
      cbv[rsel] = cb; rrv[rsel] = rr;
      jg[rsel] = s * 1024 + j;
      jh[rsel] = (s == 0) ? j : (s == 1 ? 1024 + j : -1);
    }
    float acc[4][4];
    #pragma unroll
    for (int a = 0; a < 4; ++a) { acc[a][0]=0.f; acc[a][1]=0.f; acc[a][2]=0.f; acc[a][3]=0.f; }
    for (int q = 0; q < 256; ++q) {
      float4 wd = *(const float4*)(Wdec + (size_t)q * 1024 + k0);
      #pragma unroll
      for (int a = 0; a < 4; ++a) {
        float w = Wih[(size_t)jg[a] * 256 + q];
        acc[a][0] += w * wd.x; acc[a][1] += w * wd.y;
        acc[a][2] += w * wd.z; acc[a][3] += w * wd.w;
      }
    }
    #pragma unroll
    for (int a = 0; a < 4; ++a) {
      if (jh[a] >= 0) {
        const float* wh = Whh + (size_t)jh[a] * 1024 + k0;
        acc[a][0] += wh[0]; acc[a][1] += wh[1];
        acc[a][2] += wh[2]; acc[a][3] += wh[3];
      }
      _Float16* dst = Wws + ((size_t)cbv[a] * 144 + rrv[a]) * 1024 + k0;
      dst[0] = (_Float16)acc[a][0]; dst[1] = (_Float16)acc[a][1];
      dst[2] = (_Float16)acc[a][2]; dst[3] = (_Float16)acc[a][3];
    }
  } else {                              // copy blocks: rows rr in 96..143
    #pragma unroll
    for (int rsel = 0; rsel < 4; ++rsel) {
      int cr = (blk - 768) * 4 + rsel;
      int cb = cr / 48, rr = 96 + cr % 48;
      _Float16* dst = Wws + ((size_t)cb * 144 + rr) * 1024 + k0;
      if (rr < 128) {                   // s=3: Whh[2048+j]
        int j = cb * 32 + ((rr >> 4) & 1) * 16 + (rr & 15);
        const float* src = Whh + (size_t)(2048 + j) * 1024 + k0;
        dst[0] = (_Float16)src[0]; dst[1] = (_Float16)src[1];
        dst[2] = (_Float16)src[2]; dst[3] = (_Float16)src[3];
      } else if (rr < 136) {
        const float* src = Wdec + (size_t)(cb * 8 + rr - 128) * 1024 + k0;
        dst[0] = (_Float16)src[0]; dst[1] = (_Float16)src[1];
        dst[2] = (_Float16)src[2]; dst[3] = (_Float16)src[3];
      } else {
        dst[0] = (_Float16)0.f; dst[1] = (_Float16)0.f;
        dst[2] = (_Float16)0.f; dst[3] = (_Float16)0.f;
      }
    }
  }
}

__global__ __launch_bounds__(256) void prep_bias(
    const float* __restrict__ Wih,
    const float* __restrict__ bih, const float* __restrict__ bhh,
    const float* __restrict__ bdec_in,
    float* __restrict__ br, float* __restrict__ bz, float* __restrict__ bin_,
    float* __restrict__ bhn, float* __restrict__ bdec,
    unsigned int* __restrict__ ctr)
{
  int j = blockIdx.x * 256 + threadIdx.x;   // grid 4 -> j < 1024
  if (blockIdx.x == 0) ctr[threadIdx.x] = 0u;   // reset per-mt barrier counters
  float bc0 = 0.f, bc1 = 0.f, bc2 = 0.f;
  for (int q = 0; q < 256; ++q) {
    float bd = bdec_in[q];
    bc0 += Wih[(size_t)j * 256 + q] * bd;
    bc1 += Wih[(size_t)(1024 + j) * 256 + q] * bd;
    bc2 += Wih[(size_t)(2048 + j) * 256 + q] * bd;
  }
  br[j]  = bih[j]        + bhh[j]        + bc0;
  bz[j]  = bih[1024 + j] + bhh[1024 + j] + bc1;
  bin_[j]= bih[2048 + j] + bc2;
  bhn[j] = bhh[2048 + j];
  if (j < 256) bdec[j] = bdec_in[j];
}

__global__ __launch_bounds__(256) void prep_h(
    const float* __restrict__ h0, _Float16* __restrict__ h16)
{
  int i = blockIdx.x * 256 + threadIdx.x;
  h16[i] = (_Float16)h0[i];
}

// ---------------- persistent fused kernel (cooperative, 1 block/CU) ----------------
// grid 256 = mt(8)*32 + cb(32); 256 thr = 4 waves (2x2 over [128x128] gates).
// LDS: 4 A bufs (16384 B) then 4 B bufs (18432 B). Per buffer: [row][8 kgroups
// of 16B], row stride 128 B; kgroup XOR-swizzled by (row&7), folded into the
// DMA's per-lane GLOBAL address so LDS destinations stay lane-linear.
// K-loop: ONE raw s_barrier per iter; counted vmcnt ladder (L=9 waves 0,1 /
// 8 waves 2,3; B-only Lb=5/4): ki=0->8; 1->13/12; 2..13->18/16; 14->9/8; 15->0.
__global__ __launch_bounds__(256, 1) void fused_gru(
    const _Float16* __restrict__ Wws,
    const float* __restrict__ br, const float* __restrict__ bz,
    const float* __restrict__ bin_, const float* __restrict__ bhn,
    const float* __restrict__ bdec,
    const float* __restrict__ h0,
    _Float16* __restrict__ h16A, _Float16* __restrict__ h16B,
    float* __restrict__ out,
    unsigned int* __restrict__ ctr)
{
  __shared__ __align__(16) char lds[NBUF * (ABUF + BBUF)];   // 139264 B

  const int tid = threadIdx.x;
  const int wave = tid >> 6, lane = tid & 63;
  const int mt = blockIdx.x >> 5, cb = blockIdx.x & 31;
  const int wr = wave >> 1, wc = wave & 1;
  const int col16 = lane & 15, quad = lane >> 4;

  const _Float16* __restrict__ slab = Wws + (size_t)cb * (144 * 1024);

  // DMA chunk geometry: chunk m (16 B) covers row r=m>>3, lds-kgroup c=m&7;
  // global kgroup g = c ^ (r&7) (swizzle). Wave w, issue j covers chunks
  // (w*4+j)*64 + lane. Extra B chunks 1024+tid (tid<128) cover rows 128..143.
  int offs[4];
  #pragma unroll
  for (int jj = 0; jj < 4; ++jj) {
    int m = (wave * 4 + jj) * 64 + lane;
    int r = m >> 3, c = m & 7, g = c ^ (r & 7);
    offs[jj] = r * 1024 + g * 8;       // element (half) offset
  }
  int offE;
  { int m = 1024 + tid; int r = m >> 3, c = m & 7, g = c ^ (r & 7);
    offE = r * 1024 + g * 8; }         // valid when tid < 128 (waves 0,1)

  const int swz = (quad ^ (col16 & 7)) << 4;   // ds_read swizzled col base; K-hi = ^64 B

  // loop-invariant epilogue constants (loaded once)
  const int j = cb * 32 + wc * 16 + col16;     // gate col 0..1023
  const float vbr = br[j], vbz = bz[j], vbi = bin_[j], vbh = bhn[j];
  const float vb = bdec[cb * 8 + (col16 & 7)]; // used only when col16 < 8

  // fp32 hold carried in registers across all 128 steps (C/D layout:
  // n = lane&15, m = quad*4 + reg). Seeded from h0.
  float hold[4][4];
  #pragma unroll
  for (int fm = 0; fm < 4; ++fm) {
    const int mbase = mt * 128 + 64 * wr + 16 * fm + quad * 4;
    #pragma unroll
    for (int ri = 0; ri < 4; ++ri)
      hold[fm][ri] = h0[(size_t)(mbase + ri) * 1024 + j];
  }
  // drain preloads so the vmcnt ledger starts clean
  asm volatile("s_waitcnt vmcnt(0)" ::: "memory");

  // B-only staging (weights, L2-cached): Lb = 5 (waves 0,1) / 4 (waves 2,3)
  auto issue_B = [&](int bsel, int kc) {
    char* Bb = lds + NBUF * ABUF + bsel * BBUF;
    #pragma unroll
    for (int jj = 0; jj < 4; ++jj)
      gl_lds16<0>(slab + offs[jj] + kc, Bb + (wave * 4 + jj) * 1024);
    if (wave < 2)
      gl_lds16<0>(slab + offE + kc, Bb + 16384 + wave * 1024);
  };

  const f32x4 fzero = {0.f, 0.f, 0.f, 0.f};

  // pre-loop: B sets 0..2 in flight (same every step)
  issue_B(0, 0);
  issue_B(1, 64);
  issue_B(2, 128);

  #pragma unroll 1
  for (int t = 0; t <= TS; ++t) {      // t=TS: decode-only pass for out[:,127,:]
    const _Float16* __restrict__ Abase =
        ((t & 1) ? h16B : h16A) + (size_t)mt * (128 * 1024);
    _Float16* __restrict__ o16 = (t & 1) ? h16A : h16B;

    // A-only staging (h16, device-coherent from LLC): 4 loads/set/wave
    auto issue_A = [&](int bsel, int kc) {
      char* Ab = lds + bsel * ABUF;
      #pragma unroll
      for (int jj = 0; jj < 4; ++jj)
        gl_lds16<17>(Abase + offs[jj] + kc, Ab + (wave * 4 + jj) * 1024);
    };
    auto issue_set = [&](int bsel, int kc) {
      char* Ab = lds + bsel * ABUF;
      char* Bb = lds + NBUF * ABUF + bsel * BBUF;
      #pragma unroll
      for (int jj = 0; jj < 4; ++jj) {
        gl_lds16<17>(Abase + offs[jj] + kc, Ab + (wave * 4 + jj) * 1024);
        gl_lds16<0>(slab  + offs[jj] + kc, Bb + (wave * 4 + jj) * 1024);
      }
      if (wave < 2)
        gl_lds16<0>(slab + offE + kc, Bb + 16384 + wave * 1024);
    };

    f32x4 accG[4][4]; f32x4 accD[2];
    #pragma unroll
    for (int i = 0; i < 4; ++i)
      #pragma unroll
      for (int jj = 0; jj < 4; ++jj) accG[i][jj] = fzero;
    accD[0] = fzero; accD[1] = fzero;

    // prologue: A for the 3 prestaged-B sets
    issue_A(0, 0);
    issue_A(1, 64);
    issue_A(2, 128);

    #pragma unroll 1
    for (int ki = 0; ki < 16; ++ki) {
      const int cur = ki & 3;
      // counted-vmcnt ladder (derivation in header comment):
      __builtin_amdgcn_sched_barrier(0);
      if (ki == 0) {
        asm volatile("s_waitcnt vmcnt(8)" ::: "memory");
      } else if (ki == 1) {
        if (wave < 2) asm volatile("s_waitcnt vmcnt(13)" ::: "memory");
        else          asm volatile("s_waitcnt vmcnt(12)" ::: "memory");
      } else if (ki <= 13) {
        if (wave < 2) asm volatile("s_waitcnt vmcnt(18)" ::: "memory");
        else          asm volatile("s_waitcnt vmcnt(16)" ::: "memory");
      } else if (ki == 14) {
        if (wave < 2) asm volatile("s_waitcnt vmcnt(9)" ::: "memory");
        else          asm volatile("s_waitcnt vmcnt(8)" ::: "memory");
      } else {
        asm volatile("s_waitcnt vmcnt(0)" ::: "memory");
      }
      __builtin_amdgcn_s_barrier();    // set-ki DMAs complete in all waves; all
                                       // waves finished READING buf (ki-1)&3
      __builtin_amdgcn_sched_barrier(0);

      if (ki <= 12) issue_set((ki + 3) & 3, (ki + 3) * 64);  // into freed buf

      const char* As = lds + cur * ABUF;
      const char* Bs = lds + NBUF * ABUF + cur * BBUF;

      #pragma unroll
      for (int half = 0; half < 2; ++half) {
        const int sz = swz ^ (half << 6);             // column byte offset
        f16x8 af[4], bg[4], bdv;
        #pragma unroll
        for (int fm = 0; fm < 4; ++fm)
          af[fm] = *(const f16x8*)(As + (64 * wr + 16 * fm + col16) * 128 + sz);
        #pragma unroll
        for (int fn = 0; fn < 4; ++fn)
          bg[fn] = *(const f16x8*)(Bs + (32 * fn + wc * 16 + col16) * 128 + sz);
        bdv = *(const f16x8*)(Bs + (128 + col16) * 128 + sz);
        // decode A-frags alias gate A-frags (rows 32*wave+16*d == 64*wr+16*(2*wc+d)).
        // STATIC indices + wave-uniform select -- NOT af[2*wc] (runtime index
        // sends af[] to scratch: R12's 9x regression, VALU 52%, VGPR 216).
        const f16x8 adv0 = wc ? af[2] : af[0];
        const f16x8 adv1 = wc ? af[3] : af[1];

        __builtin_amdgcn_s_setprio(1);               // T5: favor MFMA-entering wave
        #pragma unroll
        for (int fm = 0; fm < 4; ++fm)
          #pragma unroll
          for (int fn = 0; fn < 4; ++fn)
            accG[fm][fn] = __builtin_amdgcn_mfma_f32_16x16x32_f16(af[fm], bg[fn], accG[fm][fn], 0, 0, 0);
        accD[0] = __builtin_amdgcn_mfma_f32_16x16x32_f16(adv0, bdv, accD[0], 0, 0, 0);
        accD[1] = __builtin_amdgcn_mfma_f32_16x16x32_f16(adv1, bdv, accD[1], 0, 0, 0);
        __builtin_amdgcn_s_setprio(0);
      }
      // no trailing barrier: next iter's top barrier provides read-protection
    }

    // epilogue: gate math in registers; hold stays in VGPRs; h16 stores are
    // device write-through (sc0 sc1) so no cache flush is ever needed.
    if (t < TS) {
      #pragma unroll
      for (int fm = 0; fm < 4; ++fm) {
        const int mbase = mt * 128 + 64 * wr + 16 * fm + quad * 4;
        #pragma unroll
        for (int ri = 0; ri < 4; ++ri) {
          const int m = mbase + ri;
          float rg = 1.f / (1.f + __expf(-(accG[fm][0][ri] + vbr)));
          float zg = 1.f / (1.f + __expf(-(accG[fm][1][ri] + vbz)));
          float nn = tanhf(accG[fm][2][ri] + vbi + rg * (accG[fm][3][ri] + vbh));
          float hnew = (1.f - zg) * nn + zg * hold[fm][ri];
          hold[fm][ri] = hnew;
          st_h16_dev(o16 + (size_t)m * 1024 + j, (_Float16)hnew);
        }
      }
    }
    if (t > 0 && col16 < 8) {          // decode of h_{t-1} -> out[:, t-1, :]
      const int oc = cb * 8 + col16;
      #pragma unroll
      for (int d = 0; d < 2; ++d) {
        const int mbase = mt * 128 + 32 * wave + 16 * d + quad * 4;
        #pragma unroll
        for (int ri = 0; ri < 4; ++ri) {
          const int m = mbase + ri;
          out[(size_t)m * (TS * OD) + (size_t)(t - 1) * OD + oc] = accD[d][ri] + vb;
        }
      }
    }

    // per-mt inter-block barrier (32 blocks share an mt group), FENCELESS.
    // Release: __syncthreads' implicit vmcnt(0) drains sc1 stores to LLC, then
    // tid0's relaxed agent atomic. B for the NEXT step is prestaged between
    // the drain and the spin so it flies during the barrier wait. Acquire:
    // spin on relaxed agent load; post-spin sync is a RAW s_barrier (no
    // drain) so prestaged B stays in flight; A-loads are aux=17 (LLC-coherent).
    if (t < TS) {
      __syncthreads();
      issue_B(0, 0);
      issue_B(1, 64);
      issue_B(2, 128);
      if (tid == 0) {
        __hip_atomic_fetch_add(&ctr[mt * 32], 1u, __ATOMIC_RELAXED, __HIP_MEMORY_SCOPE_AGENT);
        while (__hip_atomic_load(&ctr[mt * 32], __ATOMIC_RELAXED, __HIP_MEMORY_SCOPE_AGENT)
               < 32u * (unsigned)(t + 1)) {
          __builtin_amdgcn_s_sleep(1);
        }
      }
      __builtin_amdgcn_s_barrier();
      __builtin_amdgcn_sched_barrier(0);
    }
  }
}

// ---------------- fallback step kernel (proven multi-launch path) ----------------
// Used only if the cooperative launch is rejected at enqueue time.
__global__ __launch_bounds__(256, 1) void step_kernel(
    const _Float16* __restrict__ Wws,
    const float* __restrict__ br, const float* __restrict__ bz,
    const float* __restrict__ bin_, const float* __restrict__ bhn,
    const float* __restrict__ bdec,
    const _Float16* __restrict__ h_in16, const float* __restrict__ h_in32,
    _Float16* __restrict__ h_out16, float* __restrict__ h_out32,
    float* __restrict__ out, int t)
{
  __shared__ __align__(16) char lds[2 * 16384 + 2 * 18432];

  const int tid = threadIdx.x;
  const int wave = tid >> 6, lane = tid & 63;
  const int mt = blockIdx.x >> 5, cb = blockIdx.x & 31;
  const int wr = wave >> 1, wc = wave & 1;
  const int col16 = lane & 15, quad = lane >> 4;

  const _Float16* __restrict__ slab  = Wws + (size_t)cb * (144 * 1024);
  const _Float16* __restrict__ Abase = h_in16 + (size_t)mt * (128 * 1024);

  int offs[4];
  #pragma unroll
  for (int jj = 0; jj < 4; ++jj) {
    int m = (wave * 4 + jj) * 64 + lane;
    int r = m >> 3, c = m & 7, g = c ^ (r & 7);
    offs[jj] = r * 1024 + g * 8;
  }
  int offE;
  { int m = 1024 + tid; int r = m >> 3, c = m & 7, g = c ^ (r & 7);
    offE = r * 1024 + g * 8; }

  const int swz = (quad ^ (col16 & 7)) << 4;

  f32x4 accG[4][4]; f32x4 accD[2];
  const f32x4 fzero = {0.f, 0.f, 0.f, 0.f};
  #pragma unroll
  for (int i = 0; i < 4; ++i)
    #pragma unroll
    for (int jj = 0; jj < 4; ++jj) accG[i][jj] = fzero;
  accD[0] = fzero; accD[1] = fzero;

  auto issue_dma = [&](int bsel, int kc) {
    char* Ab = lds + bsel * 16384;
    char* Bb = lds + 32768 + bsel * 18432;
    #pragma unroll
    for (int jj = 0; jj < 4; ++jj) {
      gl_lds16<0>(Abase + offs[jj] + kc, Ab + (wave * 4 + jj) * 1024);
      gl_lds16<0>(slab  + offs[jj] + kc, Bb + (wave * 4 + jj) * 1024);
    }
    if (wave < 2)
      gl_lds16<0>(slab + offE + kc, Bb + 16384 + wave * 1024);
  };

  issue_dma(0, 0);
  __syncthreads();

  #pragma unroll 1
  for (int ki = 0; ki < 16; ++ki) {
    const int cur = ki & 1;
    if (ki < 15) issue_dma(cur ^ 1, (ki + 1) * 64);
    const char* As = lds + cur * 16384;
    const char* Bs = lds + 32768 + cur * 18432;

    #pragma unroll
    for (int half = 0; half < 2; ++half) {
      const int sz = swz ^ (half << 6);
      f16x8 af[4], bg[4], bdv;
      #pragma unroll
      for (int fm = 0; fm < 4; ++fm)
        af[fm] = *(const f16x8*)(As + (64 * wr + 16 * fm + col16) * 128 + sz);
      #pragma unroll
      for (int fn = 0; fn < 4; ++fn)
        bg[fn] = *(const f16x8*)(Bs + (32 * fn + wc * 16 + col16) * 128 + sz);
      bdv = *(const f16x8*)(Bs + (128 + col16) * 128 + sz);
      const f16x8 adv0 = wc ? af[2] : af[0];   // static idx + select (no scratch)
      const f16x8 adv1 = wc ? af[3] : af[1];

      #pragma unroll
      for (int fm = 0; fm < 4; ++fm)
        #pragma unroll
        for (int fn = 0; fn < 4; ++fn)
          accG[fm][fn] = __builtin_amdgcn_mfma_f32_16x16x32_f16(af[fm], bg[fn], accG[fm][fn], 0, 0, 0);
      accD[0] = __builtin_amdgcn_mfma_f32_16x16x32_f16(adv0, bdv, accD[0], 0, 0, 0);
      accD[1] = __builtin_amdgcn_mfma_f32_16x16x32_f16(adv1, bdv, accD[1], 0, 0, 0);
    }
    __syncthreads();
  }

  if (t < TS) {
    const int jj2 = cb * 32 + wc * 16 + col16;
    const float vbr = br[jj2], vbz = bz[jj2], vbi = bin_[jj2], vbh = bhn[jj2];
    #pragma unroll
    for (int fm = 0; fm < 4; ++fm) {
      const int mbase = mt * 128 + 64 * wr + 16 * fm + quad * 4;
      #pragma unroll
      for (int ri = 0; ri < 4; ++ri) {
        const int m = mbase + ri;
        float rg = 1.f / (1.f + __expf(-(accG[fm][0][ri] + vbr)));
        float zg = 1.f / (1.f + __expf(-(accG[fm][1][ri] + vbz)));
        float nn = tanhf(accG[fm][2][ri] + vbi + rg * (accG[fm][3][ri] + vbh));
        float hold = h_in32[(size_t)m * 1024 + jj2];
        float hnew = (1.f - zg) * nn + zg * hold;
        h_out32[(size_t)m * 1024 + jj2] = hnew;
        h_out16[(size_t)m * 1024 + jj2] = (_Float16)hnew;
      }
    }
  }
  if (t > 0 && col16 < 8) {
    const int oc = cb * 8 + col16;
    const float vb = bdec[oc];
    #pragma unroll
    for (int d = 0; d < 2; ++d) {
      const int mbase = mt * 128 + 32 * wave + 16 * d + quad * 4;
      #pragma unroll
      for (int ri = 0; ri < 4; ++ri) {
        const int m = mbase + ri;
        out[(size_t)m * (TS * OD) + (size_t)(t - 1) * OD + oc] = accD[d][ri] + vb;
      }
    }
  }
}

extern "C" void kernel_launch(void* const* d_in, const int* in_sizes, int n_in,
                              void* d_out, int out_size, void* d_ws, size_t ws_size,
                              hipStream_t stream) {
  const float* h0      = (const float*)d_in[0];   // [1,1024,1024]
  const float* Wih     = (const float*)d_in[1];   // [3072,256]
  const float* Whh     = (const float*)d_in[2];   // [3072,1024]
  const float* bih     = (const float*)d_in[3];   // [3072]
  const float* bhh     = (const float*)d_in[4];   // [3072]
  const float* Wdec    = (const float*)d_in[5];   // [256,1024]
  const float* bdec_in = (const float*)d_in[6];   // [256]
  float* out = (float*)d_out;                     // [1024,128,256] fp32

  char* ws = (char*)d_ws;
  _Float16* Wws = (_Float16*)ws;                         // 9,437,184 B
  float* br   = (float*)(ws + 9437184);
  float* bz   = (float*)(ws + 9437184 + 4096);
  float* bin_ = (float*)(ws + 9437184 + 8192);
  float* bhn  = (float*)(ws + 9437184 + 12288);
  float* bdec = (float*)(ws + 9437184 + 16384);
  _Float16* h16A = (_Float16*)(ws + 9461760);            // 2 MB
  _Float16* h16B = h16A + 1024 * 1024;                   // 2 MB
  unsigned int* ctr = (unsigned int*)(ws + 9461760 + 4194304);  // 1 KB
  float* h32A = (float*)(ws + 9461760 + 4194304 + 4096); // 4 MB (fallback only)
  float* h32B = h32A + 1024 * 1024;                      // 4 MB (fallback only)
  // total ws use ~21.9 MB

  prep_w<<<1152, 256, 0, stream>>>(Wih, Whh, Wdec, Wws);
  prep_bias<<<4, 256, 0, stream>>>(Wih, bih, bhh, bdec_in, br, bz, bin_, bhn, bdec, ctr);
  prep_h<<<4096, 256, 0, stream>>>(h0, h16A);

  void* kargs[] = {
    (void*)&Wws, (void*)&br, (void*)&bz, (void*)&bin_, (void*)&bhn, (void*)&bdec,
    (void*)&h0, (void*)&h16A, (void*)&h16B, (void*)&out, (void*)&ctr
  };
  hipError_t cerr = hipLaunchCooperativeKernel((void*)fused_gru, dim3(256), dim3(256),
                                               kargs, 0, stream);
  if (cerr != hipSuccess) {
    // Fallback: proven multi-launch path (uses fp32 h carry in memory).
    for (int t = 0; t <= TS; ++t) {
      const _Float16* in16 = (t & 1) ? h16B : h16A;
      const float*    in32 = (t == 0) ? h0 : ((t & 1) ? h32B : h32A);
      _Float16*       o16  = (t & 1) ? h16A : h16B;
      float*          o32  = (t & 1) ? h32A : h32B;
      step_kernel<<<256, 256, 0, stream>>>(Wws, br, bz, bin_, bhn, bdec,
                                           in16, in32, o16, o32, out, t);
    }
  }
}

// Round 15
// 2375.927 us; speedup vs baseline: 9.9481x; 1.0869x over previous
//
#include <hip/hip_runtime.h>
#include <cstdint>
#include <cstddef>

// RecurrentDecoder: 128 sequential GRU steps fused via x_t = h_t @ W_dec^T
// => gates = h @ W_eff^T (4096 gate cols + 256 decode cols), one GEMM/step.
// Round 21 == Round 20 resubmit (R20 never executed - GPU capacity).
// R13 (scratch-fixed R12) = 2582us ~= R9 (2537) => LDS-read count + barrier
// count NOT binding. Budget: MFMA 3.9us + LDS-port 7.4us + epi 1.2 + barrier
// ~2.5 vs observed 20us/step; MFMA 21% + VALU 22% => >55% issue-idle at
// 1 wave/SIMD = latency stalls. R5's TLP test was confounded (+56% LDS bytes).
// This rev: 8 waves = 2/SIMD with SAME LDS bytes: wave (s,p) = K-half s x
// position p; each position tile computed by 2 waves over disjoint K-halves
// (sets 0-7 / 8-15); 8 K-iters; end-of-step cross-wave reduction via retired
// A-buf LDS; epilogue split by fm-halves.
// vmcnt ladder per stream: ki=0->4; 1..6->9/8 (p<2/p>=2); 7->0.
// Geometry: 256 blocks = 8 mt x 32 cb; block tile [128x144]; 1 block/CU.
// Fenceless coherence (R9-proven): h16 stores sc0|sc1, A-loads aux=17 (LLC),
// B cached in XCD L2, relaxed-atomic mt-group barrier.

#define HD 1024
#define OD 256
#define TS 128
#define ABUF 16384
#define BBUF 18432

typedef _Float16 f16x8 __attribute__((ext_vector_type(8)));
typedef float f32x4 __attribute__((ext_vector_type(4)));

// aux: 0 = normal caching (L1+L2). 17 = sc0|sc1 = device-coherent: bypass
// stale L1/L2, serve from LLC (memory-side cache = coherence point).
template <int AUX>
__device__ __forceinline__ void gl_lds16(const void* g, void* l) {
  auto gp = reinterpret_cast<const __attribute__((address_space(1))) unsigned int*>(
      reinterpret_cast<uintptr_t>(g));
  auto lp = reinterpret_cast<__attribute__((address_space(3))) unsigned int*>(
      reinterpret_cast<uintptr_t>(l));
  __builtin_amdgcn_global_load_lds(gp, lp, 16, 0, AUX);
}

// device-scope write-through 2B store (reaches LLC before vmcnt retires)
__device__ __forceinline__ void st_h16_dev(_Float16* p, _Float16 v) {
  asm volatile("global_store_short %0, %1, off sc0 sc1"
               :: "v"(p), "v"(v) : "memory");
}

__device__ __forceinline__ float fast_tanh(float x) {
  // tanh(x) = 1 - 2/(e^{2x}+1); __expf-based, saturates correctly
  return 1.f - 2.f / (__expf(2.f * x) + 1.f);
}

// ---------------- prep: build W_ws [32 cb][144 rows][1024 k] fp16 ----------------
__global__ __launch_bounds__(256) void prep_w(
    const float* __restrict__ Wih,   // [3072][256]
    const float* __restrict__ Whh,   // [3072][1024]
    const float* __restrict__ Wdec,  // [256][1024]
    _Float16* __restrict__ Wws)      // [32][144][1024]
{
  int blk = blockIdx.x, tid = threadIdx.x;
  int k0 = tid * 4;
  if (blk < 768) {                      // dot blocks: rows rr<96 (s in 0..2), 4 rows each
    int cbv[4], rrv[4], jg[4], jh[4];
    #pragma unroll
    for (int rsel = 0; rsel < 4; ++rsel) {
      int dj = blk * 4 + rsel;
      int cb = dj / 96, rr = dj % 96;
      int s = rr >> 5, wcol = (rr >> 4) & 1, p = rr & 15;
      int j = cb * 32 + wcol * 16 + p;
      cbv[rsel] = cb; rrv[rsel] = rr;
      jg[rsel] = s * 1024 + j;
      jh[rsel] = (s == 0) ? j : (s == 1 ? 1024 + j : -1);
    }
    float acc[4][4];
    #pragma unroll
    for (int a = 0; a < 4; ++a) { acc[a][0]=0.f; acc[a][1]=0.f; acc[a][2]=0.f; acc[a][3]=0.f; }
    for (int q = 0; q < 256; ++q) {
      float4 wd = *(const float4*)(Wdec + (size_t)q * 1024 + k0);
      #pragma unroll
      for (int a = 0; a < 4; ++a) {
        float w = Wih[(size_t)jg[a] * 256 + q];
        acc[a][0] += w * wd.x; acc[a][1] += w * wd.y;
        acc[a][2] += w * wd.z; acc[a][3] += w * wd.w;
      }
    }
    #pragma unroll
    for (int a = 0; a < 4; ++a) {
      if (jh[a] >= 0) {
        const float* wh = Whh + (size_t)jh[a] * 1024 + k0;
        acc[a][0] += wh[0]; acc[a][1] += wh[1];
        acc[a][2] += wh[2]; acc[a][3] += wh[3];
      }
      _Float16* dst = Wws + ((size_t)cbv[a] * 144 + rrv[a]) * 1024 + k0;
      dst[0] = (_Float16)acc[a][0]; dst[1] = (_Float16)acc[a][1];
      dst[2] = (_Float16)acc[a][2]; dst[3] = (_Float16)acc[a][3];
    }
  } else {                              // copy blocks: rows rr in 96..143
    #pragma unroll
    for (int rsel = 0; rsel < 4; ++rsel) {
      int cr = (blk - 768) * 4 + rsel;
      int cb = cr / 48, rr = 96 + cr % 48;
      _Float16* dst = Wws + ((size_t)cb * 144 + rr) * 1024 + k0;
      if (rr < 128) {                   // s=3: Whh[2048+j]
        int j = cb * 32 + ((rr >> 4) & 1) * 16 + (rr & 15);
        const float* src = Whh + (size_t)(2048 + j) * 1024 + k0;
        dst[0] = (_Float16)src[0]; dst[1] = (_Float16)src[1];
        dst[2] = (_Float16)src[2]; dst[3] = (_Float16)src[3];
      } else if (rr < 136) {
        const float* src = Wdec + (size_t)(cb * 8 + rr - 128) * 1024 + k0;
        dst[0] = (_Float16)src[0]; dst[1] = (_Float16)src[1];
        dst[2] = (_Float16)src[2]; dst[3] = (_Float16)src[3];
      } else {
        dst[0] = (_Float16)0.f; dst[1] = (_Float16)0.f;
        dst[2] = (_Float16)0.f; dst[3] = (_Float16)0.f;
      }
    }
  }
}

__global__ __launch_bounds__(256) void prep_bias(
    const float* __restrict__ Wih,
    const float* __restrict__ bih, const float* __restrict__ bhh,
    const float* __restrict__ bdec_in,
    float* __restrict__ br, float* __restrict__ bz, float* __restrict__ bin_,
    float* __restrict__ bhn, float* __restrict__ bdec,
    unsigned int* __restrict__ ctr)
{
  int j = blockIdx.x * 256 + threadIdx.x;   // grid 4 -> j < 1024
  if (blockIdx.x == 0) ctr[threadIdx.x] = 0u;   // reset per-mt barrier counters
  float bc0 = 0.f, bc1 = 0.f, bc2 = 0.f;
  for (int q = 0; q < 256; ++q) {
    float bd = bdec_in[q];
    bc0 += Wih[(size_t)j * 256 + q] * bd;
    bc1 += Wih[(size_t)(1024 + j) * 256 + q] * bd;
    bc2 += Wih[(size_t)(2048 + j) * 256 + q] * bd;
  }
  br[j]  = bih[j]        + bhh[j]        + bc0;
  bz[j]  = bih[1024 + j] + bhh[1024 + j] + bc1;
  bin_[j]= bih[2048 + j] + bc2;
  bhn[j] = bhh[2048 + j];
  if (j < 256) bdec[j] = bdec_in[j];
}

__global__ __launch_bounds__(256) void prep_h(
    const float* __restrict__ h0, _Float16* __restrict__ h16)
{
  int i = blockIdx.x * 256 + threadIdx.x;
  h16[i] = (_Float16)h0[i];
}

// ---------------- persistent fused kernel (cooperative, 512 thr, split-K) ----------------
// 8 waves: s = wave>>2 (K-half), p = wave&3 (position), wr=p>>1, wc=p&1.
// Stream s covers K-sets s*8+ki, ki=0..7. LDS: A bufs 4x16384 (idx s*2+i),
// B bufs 4x18432, + 8KB Xd. Per-wave staging = old per-wave map with p.
// Reduction: accG fm-half exchange via A-buf region (Xg 64KB), accD via Xd.
// Epilogue: wave (s,p) does fm {2s,2s+1}; decode on s==0 waves.
__global__ __launch_bounds__(512, 2) void fused_gru(
    const _Float16* __restrict__ Wws,
    const float* __restrict__ br, const float* __restrict__ bz,
    const float* __restrict__ bin_, const float* __restrict__ bhn,
    const float* __restrict__ bdec,
    const float* __restrict__ h0,
    _Float16* __restrict__ h16A, _Float16* __restrict__ h16B,
    float* __restrict__ out,
    unsigned int* __restrict__ ctr)
{
  __shared__ __align__(16) char lds[4 * (ABUF + BBUF) + 8192];   // 147456 B

  const int tid = threadIdx.x;
  const int wave = tid >> 6, lane = tid & 63;
  const int s = wave >> 2, p = wave & 3;
  const int mt = blockIdx.x >> 5, cb = blockIdx.x & 31;
  const int wr = p >> 1, wc = p & 1;
  const int col16 = lane & 15, quad = lane >> 4;

  const _Float16* __restrict__ slab = Wws + (size_t)cb * (144 * 1024);

  // DMA chunk map (per stream, 4 waves p=0..3 cover 1024 A + 1152 B chunks)
  int offs[4];
  #pragma unroll
  for (int jj = 0; jj < 4; ++jj) {
    int m = (p * 4 + jj) * 64 + lane;
    int r = m >> 3, c = m & 7, g = c ^ (r & 7);
    offs[jj] = r * 1024 + g * 8;       // element (half) offset
  }
  int offE;
  { int m = 1024 + (p * 64 + lane); int r = m >> 3, c = m & 7, g = c ^ (r & 7);
    offE = r * 1024 + g * 8; }         // valid when p < 2

  const int swz = (quad ^ (col16 & 7)) << 4;   // ds_read swizzled col base; K-hi = ^64 B

  // loop-invariant epilogue constants
  const int j = cb * 32 + wc * 16 + col16;     // gate col 0..1023
  const float vbr = br[j], vbz = bz[j], vbi = bin_[j], vbh = bhn[j];
  const float vb = bdec[cb * 8 + (col16 & 7)]; // used only when s==0 && col16<8

  // fp32 hold in regs; wave (s,p) owns fm {2s, 2s+1} rows
  float hold[2][4];
  #pragma unroll
  for (int f2 = 0; f2 < 2; ++f2) {
    const int fm = 2 * s + f2;
    const int mbase = mt * 128 + 64 * wr + 16 * fm + quad * 4;
    #pragma unroll
    for (int ri = 0; ri < 4; ++ri)
      hold[f2][ri] = h0[(size_t)(mbase + ri) * 1024 + j];
  }
  asm volatile("s_waitcnt vmcnt(0)" ::: "memory");   // clean ledger

  // B staging for stream set (s*8+ki) into B-buf s*2+i. Lb = 5 (p<2) / 4.
  auto issue_B = [&](int i, int ki) {
    char* Bb = lds + 4 * ABUF + (s * 2 + i) * BBUF;
    const int kc = (s * 8 + ki) * 64;
    #pragma unroll
    for (int jj = 0; jj < 4; ++jj)
      gl_lds16<0>(slab + offs[jj] + kc, Bb + (p * 4 + jj) * 1024);
    if (p < 2)
      gl_lds16<0>(slab + offE + kc, Bb + 16384 + p * 1024);
  };

  const f32x4 fzero = {0.f, 0.f, 0.f, 0.f};

  // pre-loop: B sets ki=0,1 of each stream in flight
  issue_B(0, 0);
  issue_B(1, 1);

  #pragma unroll 1
  for (int t = 0; t <= TS; ++t) {      // t=TS: decode-only pass for out[:,127,:]
    const _Float16* __restrict__ Abase =
        ((t & 1) ? h16B : h16A) + (size_t)mt * (128 * 1024);
    _Float16* __restrict__ o16 = (t & 1) ? h16A : h16B;

    auto issue_A = [&](int i, int ki) {
      char* Ab = lds + (s * 2 + i) * ABUF;
      const int kc = (s * 8 + ki) * 64;
      #pragma unroll
      for (int jj = 0; jj < 4; ++jj)
        gl_lds16<17>(Abase + offs[jj] + kc, Ab + (p * 4 + jj) * 1024);
    };
    auto issue_set = [&](int i, int ki) {
      char* Ab = lds + (s * 2 + i) * ABUF;
      char* Bb = lds + 4 * ABUF + (s * 2 + i) * BBUF;
      const int kc = (s * 8 + ki) * 64;
      #pragma unroll
      for (int jj = 0; jj < 4; ++jj) {
        gl_lds16<17>(Abase + offs[jj] + kc, Ab + (p * 4 + jj) * 1024);
        gl_lds16<0>(slab  + offs[jj] + kc, Bb + (p * 4 + jj) * 1024);
      }
      if (p < 2)
        gl_lds16<0>(slab + offE + kc, Bb + 16384 + p * 1024);
    };

    f32x4 accG[4][4]; f32x4 accD[2];
    #pragma unroll
    for (int i = 0; i < 4; ++i)
      #pragma unroll
      for (int jj = 0; jj < 4; ++jj) accG[i][jj] = fzero;
    accD[0] = fzero; accD[1] = fzero;

    // prologue: A for the 2 prestaged-B sets of this stream
    issue_A(0, 0);
    issue_A(1, 1);

    #pragma unroll 1
    for (int ki = 0; ki < 8; ++ki) {
      const int cur = ki & 1;
      // ladder: ki=0 -> 4 (newer = A(k1)); 1..6 -> L (1 full set newer); 7 -> 0
      __builtin_amdgcn_sched_barrier(0);
      if (ki == 0) {
        asm volatile("s_waitcnt vmcnt(4)" ::: "memory");
      } else if (ki < 7) {
        if (p < 2) asm volatile("s_waitcnt vmcnt(9)" ::: "memory");
        else       asm volatile("s_waitcnt vmcnt(8)" ::: "memory");
      } else {
        asm volatile("s_waitcnt vmcnt(0)" ::: "memory");
      }
      __builtin_amdgcn_s_barrier();    // both streams' set-ki bufs ready
      __builtin_amdgcn_sched_barrier(0);

      const char* As = lds + (s * 2 + cur) * ABUF;
      const char* Bs = lds + 4 * ABUF + (s * 2 + cur) * BBUF;

      #pragma unroll
      for (int half = 0; half < 2; ++half) {
        const int sz = swz ^ (half << 6);             // column byte offset
        f16x8 af[4], bg[4], bdv;
        #pragma unroll
        for (int fm = 0; fm < 4; ++fm)
          af[fm] = *(const f16x8*)(As + (64 * wr + 16 * fm + col16) * 128 + sz);
        #pragma unroll
        for (int fn = 0; fn < 4; ++fn)
          bg[fn] = *(const f16x8*)(Bs + (32 * fn + wc * 16 + col16) * 128 + sz);
        bdv = *(const f16x8*)(Bs + (128 + col16) * 128 + sz);
        // decode A-frag aliasing; STATIC idx + wave-uniform select (rule #20)
        const f16x8 adv0 = wc ? af[2] : af[0];
        const f16x8 adv1 = wc ? af[3] : af[1];

        __builtin_amdgcn_s_setprio(1);
        #pragma unroll
        for (int fm = 0; fm < 4; ++fm)
          #pragma unroll
          for (int fn = 0; fn < 4; ++fn)
            accG[fm][fn] = __builtin_amdgcn_mfma_f32_16x16x32_f16(af[fm], bg[fn], accG[fm][fn], 0, 0, 0);
        accD[0] = __builtin_amdgcn_mfma_f32_16x16x32_f16(adv0, bdv, accD[0], 0, 0, 0);
        accD[1] = __builtin_amdgcn_mfma_f32_16x16x32_f16(adv1, bdv, accD[1], 0, 0, 0);
        __builtin_amdgcn_s_setprio(0);
      }

      __builtin_amdgcn_sched_barrier(0);
      __builtin_amdgcn_s_barrier();    // all waves done reading their cur bufs
      __builtin_amdgcn_sched_barrier(0);
      if (ki <= 5) issue_set(cur, ki + 2);            // refill just-freed buf
    }

    // ---- split-K reduction via retired LDS ----
    __syncthreads();                                  // A-region reusable
    // write the fm-half this wave does NOT keep (s=0 keeps 0-1, writes 2-3)
    {
      char* Xg = lds + (size_t)((s * 4 + p) * 64 + lane) * 128;
      #pragma unroll
      for (int f2 = 0; f2 < 2; ++f2)
        #pragma unroll
        for (int fn = 0; fn < 4; ++fn) {
          f32x4 v = s ? accG[f2][fn] : accG[2 + f2][fn];   // static idx + select
          *(f32x4*)(Xg + (f2 * 4 + fn) * 16) = v;
        }
      if (s == 1) {
        char* Xd = lds + 4 * (ABUF + BBUF) + (size_t)(p * 64 + lane) * 32;
        *(f32x4*)(Xd)      = accD[0];
        *(f32x4*)(Xd + 16) = accD[1];
      }
    }
    __syncthreads();
    f32x4 accK[2][4];
    {
      const char* Xg = lds + (size_t)(((1 - s) * 4 + p) * 64 + lane) * 128;
      #pragma unroll
      for (int f2 = 0; f2 < 2; ++f2)
        #pragma unroll
        for (int fn = 0; fn < 4; ++fn) {
          f32x4 mine = s ? accG[2 + f2][fn] : accG[f2][fn];
          f32x4 oth = *(const f32x4*)(Xg + (f2 * 4 + fn) * 16);
          accK[f2][fn] = mine + oth;
        }
      if (s == 0) {
        const char* Xd = lds + 4 * (ABUF + BBUF) + (size_t)(p * 64 + lane) * 32;
        accD[0] += *(const f32x4*)(Xd);
        accD[1] += *(const f32x4*)(Xd + 16);
      }
    }

    // next-step B prestage, hidden under the epilogue (B-buf region is idle)
    if (t < TS) { issue_B(0, 0); issue_B(1, 1); }

    // epilogue: wave (s,p) handles fm {2s, 2s+1}
    if (t < TS) {
      #pragma unroll
      for (int f2 = 0; f2 < 2; ++f2) {
        const int fm = 2 * s + f2;
        const int mbase = mt * 128 + 64 * wr + 16 * fm + quad * 4;
        #pragma unroll
        for (int ri = 0; ri < 4; ++ri) {
          const int m = mbase + ri;
          float rg = 1.f / (1.f + __expf(-(accK[f2][0][ri] + vbr)));
          float zg = 1.f / (1.f + __expf(-(accK[f2][1][ri] + vbz)));
          float nn = fast_tanh(accK[f2][2][ri] + vbi + rg * (accK[f2][3][ri] + vbh));
          float hnew = (1.f - zg) * nn + zg * hold[f2][ri];
          hold[f2][ri] = hnew;
          st_h16_dev(o16 + (size_t)m * 1024 + j, (_Float16)hnew);
        }
      }
    }
    if (t > 0 && s == 0 && col16 < 8) {   // decode of h_{t-1} -> out[:, t-1, :]
      const int oc = cb * 8 + col16;
      #pragma unroll
      for (int d = 0; d < 2; ++d) {
        const int mbase = mt * 128 + 32 * p + 16 * d + quad * 4;
        #pragma unroll
        for (int ri = 0; ri < 4; ++ri) {
          const int m = mbase + ri;
          out[(size_t)m * (TS * OD) + (size_t)(t - 1) * OD + oc] = accD[d][ri] + vb;
        }
      }
    }

    // per-mt inter-block barrier (32 blocks/mt), FENCELESS (R9-proven).
    if (t < TS) {
      __syncthreads();                  // drains sc1 stores (and prestaged B)
      if (tid == 0) {
        __hip_atomic_fetch_add(&ctr[mt * 32], 1u, __ATOMIC_RELAXED, __HIP_MEMORY_SCOPE_AGENT);
        while (__hip_atomic_load(&ctr[mt * 32], __ATOMIC_RELAXED, __HIP_MEMORY_SCOPE_AGENT)
               < 32u * (unsigned)(t + 1)) {
          __builtin_amdgcn_s_sleep(1);
        }
      }
      __builtin_amdgcn_s_barrier();     // raw: prestaged B stays in flight
      __builtin_amdgcn_sched_barrier(0);
    }
  }
}

// ---------------- fallback step kernel (proven multi-launch path) ----------------
__global__ __launch_bounds__(256, 1) void step_kernel(
    const _Float16* __restrict__ Wws,
    const float* __restrict__ br, const float* __restrict__ bz,
    const float* __restrict__ bin_, const float* __restrict__ bhn,
    const float* __restrict__ bdec,
    const _Float16* __restrict__ h_in16, const float* __restrict__ h_in32,
    _Float16* __restrict__ h_out16, float* __restrict__ h_out32,
    float* __restrict__ out, int t)
{
  __shared__ __align__(16) char lds[2 * 16384 + 2 * 18432];

  const int tid = threadIdx.x;
  const int wave = tid >> 6, lane = tid & 63;
  const int mt = blockIdx.x >> 5, cb = blockIdx.x & 31;
  const int wr = wave >> 1, wc = wave & 1;
  const int col16 = lane & 15, quad = lane >> 4;

  const _Float16* __restrict__ slab  = Wws + (size_t)cb * (144 * 1024);
  const _Float16* __restrict__ Abase = h_in16 + (size_t)mt * (128 * 1024);

  int offs[4];
  #pragma unroll
  for (int jj = 0; jj < 4; ++jj) {
    int m = (wave * 4 + jj) * 64 + lane;
    int r = m >> 3, c = m & 7, g = c ^ (r & 7);
    offs[jj] = r * 1024 + g * 8;
  }
  int offE;
  { int m = 1024 + tid; int r = m >> 3, c = m & 7, g = c ^ (r & 7);
    offE = r * 1024 + g * 8; }

  const int swz = (quad ^ (col16 & 7)) << 4;

  f32x4 accG[4][4]; f32x4 accD[2];
  const f32x4 fzero = {0.f, 0.f, 0.f, 0.f};
  #pragma unroll
  for (int i = 0; i < 4; ++i)
    #pragma unroll
    for (int jj = 0; jj < 4; ++jj) accG[i][jj] = fzero;
  accD[0] = fzero; accD[1] = fzero;

  auto issue_dma = [&](int bsel, int kc) {
    char* Ab = lds + bsel * 16384;
    char* Bb = lds + 32768 + bsel * 18432;
    #pragma unroll
    for (int jj = 0; jj < 4; ++jj) {
      gl_lds16<0>(Abase + offs[jj] + kc, Ab + (wave * 4 + jj) * 1024);
      gl_lds16<0>(slab  + offs[jj] + kc, Bb + (wave * 4 + jj) * 1024);
    }
    if (wave < 2)
      gl_lds16<0>(slab + offE + kc, Bb + 16384 + wave * 1024);
  };

  issue_dma(0, 0);
  __syncthreads();

  #pragma unroll 1
  for (int ki = 0; ki < 16; ++ki) {
    const int cur = ki & 1;
    if (ki < 15) issue_dma(cur ^ 1, (ki + 1) * 64);
    const char* As = lds + cur * 16384;
    const char* Bs = lds + 32768 + cur * 18432;

    #pragma unroll
    for (int half = 0; half < 2; ++half) {
      const int sz = swz ^ (half << 6);
      f16x8 af[4], bg[4], bdv;
      #pragma unroll
      for (int fm = 0; fm < 4; ++fm)
        af[fm] = *(const f16x8*)(As + (64 * wr + 16 * fm + col16) * 128 + sz);
      #pragma unroll
      for (int fn = 0; fn < 4; ++fn)
        bg[fn] = *(const f16x8*)(Bs + (32 * fn + wc * 16 + col16) * 128 + sz);
      bdv = *(const f16x8*)(Bs + (128 + col16) * 128 + sz);
      const f16x8 adv0 = wc ? af[2] : af[0];
      const f16x8 adv1 = wc ? af[3] : af[1];

      #pragma unroll
      for (int fm = 0; fm < 4; ++fm)
        #pragma unroll
        for (int fn = 0; fn < 4; ++fn)
          accG[fm][fn] = __builtin_amdgcn_mfma_f32_16x16x32_f16(af[fm], bg[fn], accG[fm][fn], 0, 0, 0);
      accD[0] = __builtin_amdgcn_mfma_f32_16x16x32_f16(adv0, bdv, accD[0], 0, 0, 0);
      accD[1] = __builtin_amdgcn_mfma_f32_16x16x32_f16(adv1, bdv, accD[1], 0, 0, 0);
    }
    __syncthreads();
  }

  if (t < TS) {
    const int jj2 = cb * 32 + wc * 16 + col16;
    const float vbr = br[jj2], vbz = bz[jj2], vbi = bin_[jj2], vbh = bhn[jj2];
    #pragma unroll
    for (int fm = 0; fm < 4; ++fm) {
      const int mbase = mt * 128 + 64 * wr + 16 * fm + quad * 4;
      #pragma unroll
      for (int ri = 0; ri < 4; ++ri) {
        const int m = mbase + ri;
        float rg = 1.f / (1.f + __expf(-(accG[fm][0][ri] + vbr)));
        float zg = 1.f / (1.f + __expf(-(accG[fm][1][ri] + vbz)));
        float nn = fast_tanh(accG[fm][2][ri] + vbi + rg * (accG[fm][3][ri] + vbh));
        float hold = h_in32[(size_t)m * 1024 + jj2];
        float hnew = (1.f - zg) * nn + zg * hold;
        h_out32[(size_t)m * 1024 + jj2] = hnew;
        h_out16[(size_t)m * 1024 + jj2] = (_Float16)hnew;
      }
    }
  }
  if (t > 0 && col16 < 8) {
    const int oc = cb * 8 + col16;
    const float vb = bdec[oc];
    #pragma unroll
    for (int d = 0; d < 2; ++d) {
      const int mbase = mt * 128 + 32 * wave + 16 * d + quad * 4;
      #pragma unroll
      for (int ri = 0; ri < 4; ++ri) {
        const int m = mbase + ri;
        out[(size_t)m * (TS * OD) + (size_t)(t - 1) * OD + oc] = accD[d][ri] + vb;
      }
    }
  }
}

extern "C" void kernel_launch(void* const* d_in, const int* in_sizes, int n_in,
                              void* d_out, int out_size, void* d_ws, size_t ws_size,
                              hipStream_t stream) {
  const float* h0      = (const float*)d_in[0];   // [1,1024,1024]
  const float* Wih     = (const float*)d_in[1];   // [3072,256]
  const float* Whh     = (const float*)d_in[2];   // [3072,1024]
  const float* bih     = (const float*)d_in[3];   // [3072]
  const float* bhh     = (const float*)d_in[4];   // [3072]
  const float* Wdec    = (const float*)d_in[5];   // [256,1024]
  const float* bdec_in = (const float*)d_in[6];   // [256]
  float* out = (float*)d_out;                     // [1024,128,256] fp32

  char* ws = (char*)d_ws;
  _Float16* Wws = (_Float16*)ws;                         // 9,437,184 B
  float* br   = (float*)(ws + 9437184);
  float* bz   = (float*)(ws + 9437184 + 4096);
  float* bin_ = (float*)(ws + 9437184 + 8192);
  float* bhn  = (float*)(ws + 9437184 + 12288);
  float* bdec = (float*)(ws + 9437184 + 16384);
  _Float16* h16A = (_Float16*)(ws + 9461760);            // 2 MB
  _Float16* h16B = h16A + 1024 * 1024;                   // 2 MB
  unsigned int* ctr = (unsigned int*)(ws + 9461760 + 4194304);  // 1 KB
  float* h32A = (float*)(ws + 9461760 + 4194304 + 4096); // 4 MB (fallback only)
  float* h32B = h32A + 1024 * 1024;                      // 4 MB (fallback only)
  // total ws use ~21.9 MB

  prep_w<<<1152, 256, 0, stream>>>(Wih, Whh, Wdec, Wws);
  prep_bias<<<4, 256, 0, stream>>>(Wih, bih, bhh, bdec_in, br, bz, bin_, bhn, bdec, ctr);
  prep_h<<<4096, 256, 0, stream>>>(h0, h16A);

  void* kargs[] = {
    (void*)&Wws, (void*)&br, (void*)&bz, (void*)&bin_, (void*)&bhn, (void*)&bdec,
    (void*)&h0, (void*)&h16A, (void*)&h16B, (void*)&out, (void*)&ctr
  };
  hipError_t cerr = hipLaunchCooperativeKernel((void*)fused_gru, dim3(256), dim3(512),
                                               kargs, 0, stream);
  if (cerr != hipSuccess) {
    // Fallback: proven multi-launch path (uses fp32 h carry in memory).
    for (int t = 0; t <= TS; ++t) {
      const _Float16* in16 = (t & 1) ? h16B : h16A;
      const float*    in32 = (t == 0) ? h0 : ((t & 1) ? h32B : h32A);
      _Float16*       o16  = (t & 1) ? h16A : h16B;
      float*          o32  = (t & 1) ? h32A : h32B;
      step_kernel<<<256, 256, 0, stream>>>(Wws, br, bz, bin_, bhn, bdec,
                                           in16, in32, o16, o32, out, t);
    }
  }
}